// Round 3
// baseline (12686.664 us; speedup 1.0000x reference)
//
#include <hip/hip_runtime.h>

#define BB 256
#define TT 2048
#define NN 64

__global__ __launch_bounds__(64, 1)
void crf_viterbi_kernel(const float* __restrict__ x,
                        const int* __restrict__ seq_len,
                        const float* __restrict__ trans,
                        float* __restrict__ out) {
  const int b = blockIdx.x;
  const int j = threadIdx.x;  // 0..63, one lane per state

  __shared__ __align__(16) float alpha_s[2][NN];
  __shared__ unsigned char bp_s[(TT - 1) * NN];  // 131008 B backpointers
  __shared__ int s_last;
  __shared__ float s_best;

  const float* xb = x + (size_t)b * TT * NN;
  const int slen = seq_len[b];

  // trans column j -> registers (coalesced: for fixed i, lanes j contiguous)
  float tc[NN];
#pragma unroll
  for (int i = 0; i < NN; ++i) tc[i] = trans[i * NN + j];

  // alpha0 = x[:,0]
  alpha_s[0][j] = xb[j];
  __syncthreads();

  int cur = 0;
  float xnext = (slen > 1) ? xb[NN + j] : 0.0f;  // prefetch x_t one step ahead

  for (int t = 1; t < slen; ++t) {
    float xv = xnext;
    if (t + 1 < slen) xnext = xb[(size_t)(t + 1) * NN + j];

    // candidates: all 64 adds independent (latency hidden by issue)
    float c[NN];
#pragma unroll
    for (int k = 0; k < 16; ++k) {
      float4 a4 = *reinterpret_cast<const float4*>(&alpha_s[cur][4 * k]);
      c[4 * k + 0] = a4.x + tc[4 * k + 0];
      c[4 * k + 1] = a4.y + tc[4 * k + 1];
      c[4 * k + 2] = a4.z + tc[4 * k + 2];
      c[4 * k + 3] = a4.w + tc[4 * k + 3];
    }

    // tournament tree argmax, depth 6 (dep chain ~48 cyc vs ~512 linear).
    // strict (hi > lo) keeps the lower index on ties -> first-occurrence,
    // identical to jnp.argmax; max value itself is order-independent.
    float v[32];
    int bi[32];
#pragma unroll
    for (int i = 0; i < 32; ++i) {
      bool g = c[2 * i + 1] > c[2 * i];
      v[i] = g ? c[2 * i + 1] : c[2 * i];
      bi[i] = g ? 2 * i + 1 : 2 * i;
    }
#pragma unroll
    for (int w = 16; w >= 1; w >>= 1) {
#pragma unroll
      for (int i = 0; i < w; ++i) {
        bool g = v[2 * i + 1] > v[2 * i];
        v[i] = g ? v[2 * i + 1] : v[2 * i];
        bi[i] = g ? bi[2 * i + 1] : bi[2 * i];
      }
    }

    alpha_s[cur ^ 1][j] = v[0] + xv;
    bp_s[(t - 1) * NN + j] = (unsigned char)bi[0];
    __syncthreads();  // single-wave barrier: orders LDS write -> next-step reads
    cur ^= 1;
  }

  // final max/argmax over states (first-occurrence tie-break, matches jnp.argmax)
  if (j == 0) {
    float best = alpha_s[cur][0];
    int bi0 = 0;
    for (int i = 1; i < NN; ++i) {
      float v0 = alpha_s[cur][i];
      if (v0 > best) { best = v0; bi0 = i; }
    }
    s_last = bi0;
    s_best = best;
  }
  __syncthreads();
  const int last = s_last;
  const float lastf = (float)last;

  // tags[t] = last for all t >= slen-1 (identity backpointers), coalesced
  for (int t = slen - 1 + j; t < TT; t += NN) out[b * TT + t] = lastf;

  if (j == 0) {
    // scores: exact fp32 value (whole d_out is float32)
    out[BB * TT + b] = s_best;

    // traceback: tags[t] = bp_{t+1}[tags[t+1]], bp_{t+1} stored at LDS row t
    int tag = last;
    for (int t = slen - 2; t >= 0; --t) {
      tag = bp_s[t * NN + tag];
      out[b * TT + t] = (float)tag;
    }
  }
}

extern "C" void kernel_launch(void* const* d_in, const int* in_sizes, int n_in,
                              void* d_out, int out_size, void* d_ws, size_t ws_size,
                              hipStream_t stream) {
  const float* x = (const float*)d_in[0];
  const int* seq_len = (const int*)d_in[1];
  const float* trans = (const float*)d_in[2];
  float* out = (float*)d_out;

  crf_viterbi_kernel<<<BB, 64, 0, stream>>>(x, seq_len, trans, out);
}

// Round 4
// 3749.921 us; speedup vs baseline: 3.3832x; 3.3832x over previous
//
#include <hip/hip_runtime.h>

#define BB 256
#define TT 2048
#define NN 64

__global__ __launch_bounds__(64, 1)
void crf_viterbi_kernel(const float* __restrict__ x,
                        const int* __restrict__ seq_len,
                        const float* __restrict__ trans,
                        float* __restrict__ out) {
  const int b = blockIdx.x;
  const int j = threadIdx.x;  // 0..63, one lane per state

  __shared__ __align__(16) float alpha_s[2][NN];
  __shared__ unsigned char bp_s[(TT - 1) * NN];  // 131008 B backpointers
  __shared__ int s_last;
  __shared__ float s_best;

  const float* xb = x + (size_t)b * TT * NN;
  const int slen = seq_len[b];

  // trans column j -> registers (coalesced: for fixed i, lanes j contiguous)
  float tc[NN];
#pragma unroll
  for (int i = 0; i < NN; ++i) tc[i] = trans[i * NN + j];

  // alpha0 = x[:,0]
  alpha_s[0][j] = xb[j];
  __syncthreads();

  int cur = 0;
  float xnext = (slen > 1) ? xb[NN + j] : 0.0f;  // prefetch x_t one step ahead

  for (int t = 1; t < slen; ++t) {
    float xv = xnext;
    if (t + 1 < slen) xnext = xb[(size_t)(t + 1) * NN + j];

    // Group-of-4 reduce fused into the float4 read: only gv[16]/gi[16] stay
    // live (register-friendly; R3's c[64]+v[32]+bi[32] spilled to scratch).
    // Adjacent-pair combines with strict (right > left) keep the lower index
    // on ties -> exact first-occurrence argmax (left always covers smaller i).
    float gv[16];
    int gi[16];
#pragma unroll
    for (int k = 0; k < 16; ++k) {
      float4 a4 = *reinterpret_cast<const float4*>(&alpha_s[cur][4 * k]);
      float c0 = a4.x + tc[4 * k + 0];
      float c1 = a4.y + tc[4 * k + 1];
      float c2 = a4.z + tc[4 * k + 2];
      float c3 = a4.w + tc[4 * k + 3];
      bool g01 = c1 > c0;
      float v01 = g01 ? c1 : c0;
      int i01 = g01 ? 1 : 0;
      bool g23 = c3 > c2;
      float v23 = g23 ? c3 : c2;
      int i23 = g23 ? 3 : 2;
      bool g = v23 > v01;
      gv[k] = g ? v23 : v01;
      gi[k] = 4 * k + (g ? i23 : i01);
    }
    // adjacent-pair tree over the 16 group winners (depth 4)
#pragma unroll
    for (int i = 0; i < 8; ++i) {
      bool g = gv[2 * i + 1] > gv[2 * i];
      gv[i] = g ? gv[2 * i + 1] : gv[2 * i];
      gi[i] = g ? gi[2 * i + 1] : gi[2 * i];
    }
#pragma unroll
    for (int i = 0; i < 4; ++i) {
      bool g = gv[2 * i + 1] > gv[2 * i];
      gv[i] = g ? gv[2 * i + 1] : gv[2 * i];
      gi[i] = g ? gi[2 * i + 1] : gi[2 * i];
    }
#pragma unroll
    for (int i = 0; i < 2; ++i) {
      bool g = gv[2 * i + 1] > gv[2 * i];
      gv[i] = g ? gv[2 * i + 1] : gv[2 * i];
      gi[i] = g ? gi[2 * i + 1] : gi[2 * i];
    }
    {
      bool g = gv[1] > gv[0];
      gv[0] = g ? gv[1] : gv[0];
      gi[0] = g ? gi[1] : gi[0];
    }

    alpha_s[cur ^ 1][j] = gv[0] + xv;
    bp_s[(t - 1) * NN + j] = (unsigned char)gi[0];
    __syncthreads();  // single-wave barrier: orders LDS write -> next-step reads
    cur ^= 1;
  }

  // final max/argmax over states (first-occurrence tie-break, matches jnp.argmax)
  if (j == 0) {
    float best = alpha_s[cur][0];
    int bi0 = 0;
    for (int i = 1; i < NN; ++i) {
      float v0 = alpha_s[cur][i];
      if (v0 > best) { best = v0; bi0 = i; }
    }
    s_last = bi0;
    s_best = best;
  }
  __syncthreads();
  const int last = s_last;
  const float lastf = (float)last;

  // tags[t] = last for all t >= slen-1 (identity backpointers), coalesced
  for (int t = slen - 1 + j; t < TT; t += NN) out[b * TT + t] = lastf;

  if (j == 0) {
    // scores: exact fp32 value (whole d_out is float32)
    out[BB * TT + b] = s_best;

    // traceback: tags[t] = bp_{t+1}[tags[t+1]], bp_{t+1} stored at LDS row t
    int tag = last;
    for (int t = slen - 2; t >= 0; --t) {
      tag = bp_s[t * NN + tag];
      out[b * TT + t] = (float)tag;
    }
  }
}

extern "C" void kernel_launch(void* const* d_in, const int* in_sizes, int n_in,
                              void* d_out, int out_size, void* d_ws, size_t ws_size,
                              hipStream_t stream) {
  const float* x = (const float*)d_in[0];
  const int* seq_len = (const int*)d_in[1];
  const float* trans = (const float*)d_in[2];
  float* out = (float*)d_out;

  crf_viterbi_kernel<<<BB, 64, 0, stream>>>(x, seq_len, trans, out);
}

// Round 5
// 1259.355 us; speedup vs baseline: 10.0739x; 2.9777x over previous
//
#include <hip/hip_runtime.h>

#define BB 256
#define TT 2048
#define NN 64

// 4-chain argmax step: strict > keeps lower index on ties (first-occurrence)
#define STEP(mq, bq, val, idx)                    \
  {                                               \
    float c_ = (val) + tc[idx];                   \
    bool g_ = c_ > (mq);                          \
    (mq) = g_ ? c_ : (mq);                        \
    (bq) = g_ ? (idx) : (bq);                     \
  }

__global__ __launch_bounds__(64, 1)
void crf_viterbi_kernel(const float* __restrict__ x,
                        const int* __restrict__ seq_len,
                        const float* __restrict__ trans,
                        float* __restrict__ out) {
  const int b = blockIdx.x;
  const int j = threadIdx.x;  // 0..63, one lane per state

  // Single-wave block: DS-pipe ops complete in order per wave, so the
  // alpha ping-pong write->read needs NO barrier. No __syncthreads()
  // anywhere => compiler never emits the vmcnt(0)/lgkmcnt(0) drain that
  // put the x-prefetch on the critical path.
  __shared__ __align__(16) float alpha_s[2][NN];
  __shared__ unsigned char bp_s[(TT - 1) * NN];  // 131008 B backpointers

  const float* xb = x + (size_t)b * TT * NN;
  const int slen = seq_len[b];

  // trans column j -> registers (coalesced: for fixed i, lanes j contiguous)
  float tc[NN];
#pragma unroll
  for (int i = 0; i < NN; ++i) tc[i] = trans[i * NN + j];

  // alpha0 = x[:,0]
  alpha_s[0][j] = xb[j];

  int cur = 0;
  float xnext = xb[NN + j];  // prefetch t=1 (in-bounds: TT >= 2)

  for (int t = 1; t < slen; ++t) {
    float xv = xnext;
    int tn = (t + 1 < TT) ? t + 1 : TT - 1;  // clamp: stays in batch region
    xnext = xb[(size_t)tn * NN + j];

    // 4 independent chains over contiguous i-blocks; ~130-cyc dep chain,
    // only 8 extra live registers (R4's 32-wide tree spilled past the cap).
    float m0 = -INFINITY, m1 = -INFINITY, m2 = -INFINITY, m3 = -INFINITY;
    int b0 = 0, b1 = 16, b2 = 32, b3 = 48;
#pragma unroll
    for (int k = 0; k < 4; ++k) {
      float4 a0 = *reinterpret_cast<const float4*>(&alpha_s[cur][0 + 4 * k]);
      float4 a1 = *reinterpret_cast<const float4*>(&alpha_s[cur][16 + 4 * k]);
      float4 a2 = *reinterpret_cast<const float4*>(&alpha_s[cur][32 + 4 * k]);
      float4 a3 = *reinterpret_cast<const float4*>(&alpha_s[cur][48 + 4 * k]);
      STEP(m0, b0, a0.x, 0 + 4 * k + 0)
      STEP(m1, b1, a1.x, 16 + 4 * k + 0)
      STEP(m2, b2, a2.x, 32 + 4 * k + 0)
      STEP(m3, b3, a3.x, 48 + 4 * k + 0)
      STEP(m0, b0, a0.y, 0 + 4 * k + 1)
      STEP(m1, b1, a1.y, 16 + 4 * k + 1)
      STEP(m2, b2, a2.y, 32 + 4 * k + 1)
      STEP(m3, b3, a3.y, 48 + 4 * k + 1)
      STEP(m0, b0, a0.z, 0 + 4 * k + 2)
      STEP(m1, b1, a1.z, 16 + 4 * k + 2)
      STEP(m2, b2, a2.z, 32 + 4 * k + 2)
      STEP(m3, b3, a3.z, 48 + 4 * k + 2)
      STEP(m0, b0, a0.w, 0 + 4 * k + 3)
      STEP(m1, b1, a1.w, 16 + 4 * k + 3)
      STEP(m2, b2, a2.w, 32 + 4 * k + 3)
      STEP(m3, b3, a3.w, 48 + 4 * k + 3)
    }
    // combine: left operand always covers smaller indices -> strict > on the
    // right keeps exact first-occurrence argmax
    {
      bool g = m1 > m0; m0 = g ? m1 : m0; b0 = g ? b1 : b0;
    }
    {
      bool g = m3 > m2; m2 = g ? m3 : m2; b2 = g ? b3 : b2;
    }
    {
      bool g = m2 > m0; m0 = g ? m2 : m0; b0 = g ? b2 : b0;
    }

    alpha_s[cur ^ 1][j] = m0 + xv;
    bp_s[(t - 1) * NN + j] = (unsigned char)b0;
    cur ^= 1;  // no barrier: single-wave in-order DS pipe
  }

  // final max/argmax over states, computed redundantly by every lane via
  // broadcast LDS reads (no barrier / no cross-lane op needed).
  float best = -INFINITY;
  int last = 0;
#pragma unroll
  for (int i = 0; i < NN; ++i) {
    float v = alpha_s[cur][i];
    bool g = v > best;
    best = g ? v : best;
    last = g ? i : last;
  }
  const float lastf = (float)last;

  // tags[t] = last for all t >= slen-1 (identity backpointers), coalesced
  for (int t = slen - 1 + j; t < TT; t += NN) out[b * TT + t] = lastf;

  if (j == 0) {
    // scores: exact fp32 value (whole d_out is float32)
    out[BB * TT + b] = best;

    // traceback: tags[t] = bp_{t+1}[tags[t+1]], bp_{t+1} stored at LDS row t
    int tag = last;
    for (int t = slen - 2; t >= 0; --t) {
      tag = bp_s[t * NN + tag];
      out[b * TT + t] = (float)tag;
    }
  }
}

extern "C" void kernel_launch(void* const* d_in, const int* in_sizes, int n_in,
                              void* d_out, int out_size, void* d_ws, size_t ws_size,
                              hipStream_t stream) {
  const float* x = (const float*)d_in[0];
  const int* seq_len = (const int*)d_in[1];
  const float* trans = (const float*)d_in[2];
  float* out = (float*)d_out;

  crf_viterbi_kernel<<<BB, 64, 0, stream>>>(x, seq_len, trans, out);
}

// Round 6
// 1257.579 us; speedup vs baseline: 10.0882x; 1.0014x over previous
//
#include <hip/hip_runtime.h>

#define BB 256
#define TT 2048
#define NN 64

__global__ __launch_bounds__(256, 1)
void crf_viterbi_kernel(const float* __restrict__ x,
                        const int* __restrict__ seq_len,
                        const float* __restrict__ trans,
                        float* __restrict__ out) {
  const int b = blockIdx.x;
  const int tid = threadIdx.x;
  const int j = tid & 63;   // state column this lane owns
  const int w = tid >> 6;   // wave id 0..3
  const int ibase = w << 4; // this wave's i-range start

  // Partials are the ONLY cross-wave data: double-buffered so one barrier
  // per step suffices (t+2's write to parity p is gated by barrier(t+1),
  // which opens only after all waves finished their t-reads of parity p).
  __shared__ __align__(16) float2 part_s[2][4][NN];
  __shared__ unsigned char bp_s[(TT - 1) * NN];  // 131008 B backpointers

  const float* xb = x + (size_t)b * TT * NN;
  const int slen = seq_len[b];

  // this wave's 16-row slice of trans, column j (coalesced)
  float tc[16];
#pragma unroll
  for (int k = 0; k < 16; ++k) tc[k] = trans[(ibase + k) * NN + j];

  // alpha[j] lives in lane j of EVERY wave (each wave combines redundantly)
  float alpha = xb[j];
  float xnext = xb[NN + j];  // prefetch x[1] (TT >= 2)

  for (int t = 1; t < slen; ++t) {
    float xv = xnext;
    {
      int tn = (t + 1 < TT) ? (t + 1) : (TT - 1);  // clamped, stays in batch
      xnext = xb[(size_t)tn * NN + j];  // issued at top: ~1 step old at the
    }                                   // barrier's vmcnt(0) drain -> hidden

    // partial argmax over i in [ibase, ibase+16): alpha[i] via in-wave
    // readlane broadcast (no LDS, no sync); strict > + ascending k keeps
    // first-occurrence semantics.
    float m, bi;
    {
      float a0 = __int_as_float(__builtin_amdgcn_readlane(__float_as_int(alpha), ibase));
      m = a0 + tc[0];
      bi = (float)ibase;
    }
#pragma unroll
    for (int k = 1; k < 16; ++k) {
      float ak = __int_as_float(__builtin_amdgcn_readlane(__float_as_int(alpha), ibase + k));
      float c = ak + tc[k];
      bool g = c > m;
      m = g ? c : m;
      bi = g ? (float)(ibase + k) : bi;
    }
    const int par = t & 1;
    part_s[par][w][j] = make_float2(m, bi);
    __syncthreads();

    // combine in ascending wave order (i ascending) with strict > :
    // exact first-occurrence argmax; every wave does this redundantly.
    float2 p0 = part_s[par][0][j];
    float2 p1 = part_s[par][1][j];
    float2 p2 = part_s[par][2][j];
    float2 p3 = part_s[par][3][j];
    float bv = p0.x, bidx = p0.y;
    { bool g = p1.x > bv; bv = g ? p1.x : bv; bidx = g ? p1.y : bidx; }
    { bool g = p2.x > bv; bv = g ? p2.x : bv; bidx = g ? p2.y : bidx; }
    { bool g = p3.x > bv; bv = g ? p3.x : bv; bidx = g ? p3.y : bidx; }

    alpha = bv + xv;
    if (w == 0) bp_s[(t - 1) * NN + j] = (unsigned char)(int)bidx;
    // no second barrier: parity double-buffer covers the WAR hazard
  }

  // final argmax over states: in-wave butterfly with explicit index
  // tie-break (smaller index wins) -> exact jnp.argmax; all waves converge.
  float best = alpha;
  int last = j;
#pragma unroll
  for (int mask = 1; mask < 64; mask <<= 1) {
    float ov = __shfl_xor(best, mask, 64);
    int oi = __shfl_xor(last, mask, 64);
    bool take = (ov > best) || (ov == best && oi < last);
    best = take ? ov : best;
    last = take ? oi : last;
  }
  const float lastf = (float)last;

  // tags[t] = last for all t >= slen-1 (identity backpointers), coalesced
  for (int t = slen - 1 + tid; t < TT; t += 256) out[b * TT + t] = lastf;

  if (tid == 0) {
    // scores: exact fp32 value (d_out is float32)
    out[BB * TT + b] = best;

    // traceback: tags[t] = bp_{t+1}[tags[t+1]], bp_{t+1} stored at LDS row t.
    // tid0 is in wave 0 which wrote bp_s -> in-order DS pipe, no barrier.
    int tag = last;
    for (int t = slen - 2; t >= 0; --t) {
      tag = bp_s[t * NN + tag];
      out[b * TT + t] = (float)tag;
    }
  }
}

extern "C" void kernel_launch(void* const* d_in, const int* in_sizes, int n_in,
                              void* d_out, int out_size, void* d_ws, size_t ws_size,
                              hipStream_t stream) {
  const float* x = (const float*)d_in[0];
  const int* seq_len = (const int*)d_in[1];
  const float* trans = (const float*)d_in[2];
  float* out = (float*)d_out;

  crf_viterbi_kernel<<<BB, 256, 0, stream>>>(x, seq_len, trans, out);
}

// Round 7
// 943.346 us; speedup vs baseline: 13.4486x; 1.3331x over previous
//
#include <hip/hip_runtime.h>

#define BB 256
#define TT 2048
#define NN 64

// one reduction link: strict > keeps lower index on ties (first-occurrence)
#define STEP16(mq, bq, kk)                                               \
  {                                                                      \
    float ak_ = __int_as_float(                                          \
        __builtin_amdgcn_readlane(__float_as_int(alpha), ibase + (kk))); \
    float c_ = ak_ + tc[kk];                                             \
    bool g_ = c_ > (mq);                                                 \
    (mq) = g_ ? c_ : (mq);                                               \
    (bq) = g_ ? ibase + (kk) : (bq);                                     \
  }

__global__ __launch_bounds__(256, 1)
void crf_viterbi_kernel(const float* __restrict__ x,
                        const int* __restrict__ seq_len,
                        const float* __restrict__ trans,
                        float* __restrict__ out) {
  const int b = blockIdx.x;
  const int tid = threadIdx.x;
  const int j = tid & 63;   // state column this lane owns
  const int w = tid >> 6;   // wave id 0..3
  const int ibase = w << 4; // this wave's i-range start

  // Partials double-buffered by step parity: one barrier per step suffices
  // (wave A's t+2 write to parity p is gated by barrier(t+1), which opens
  // only after every wave finished its t-read of parity p).
  __shared__ __align__(16) float2 part_s[2][4][NN];
  __shared__ unsigned char bp_s[(TT - 1) * NN];  // 131008 B backpointers

  const float* xb = x + (size_t)b * TT * NN;
  const int slen = seq_len[b];

  // this wave's 16-row slice of trans, column j (coalesced)
  float tc[16];
#pragma unroll
  for (int k = 0; k < 16; ++k) tc[k] = trans[(ibase + k) * NN + j];

  // alpha[j] lives in lane j of EVERY wave (each wave combines redundantly)
  float alpha = xb[j];
  // 2-step-deep prefetch: the consumed load is ~2 steps old at its use,
  // and the raw barrier below never drains vmcnt -> loads stay in flight.
  float xn1 = xb[NN + j];
  float xn2 = xb[2 * NN + j];

  for (int t = 1; t < slen; ++t) {
    float xv = xn1;
    xn1 = xn2;
    {
      int tn = (t + 2 < TT) ? (t + 2) : (TT - 1);  // clamped, stays in batch
      xn2 = xb[(size_t)tn * NN + j];
    }

    // partial argmax over i in [ibase, ibase+16): alpha via in-wave readlane
    // (pure VALU, no LDS RAW). 4 sub-chains of 4 -> dep depth ~6 links.
    float m0, m1, m2, m3;
    int b0, b1, b2, b3;
    {
      float a_ = __int_as_float(__builtin_amdgcn_readlane(__float_as_int(alpha), ibase + 0));
      m0 = a_ + tc[0]; b0 = ibase + 0;
      a_ = __int_as_float(__builtin_amdgcn_readlane(__float_as_int(alpha), ibase + 4));
      m1 = a_ + tc[4]; b1 = ibase + 4;
      a_ = __int_as_float(__builtin_amdgcn_readlane(__float_as_int(alpha), ibase + 8));
      m2 = a_ + tc[8]; b2 = ibase + 8;
      a_ = __int_as_float(__builtin_amdgcn_readlane(__float_as_int(alpha), ibase + 12));
      m3 = a_ + tc[12]; b3 = ibase + 12;
    }
    STEP16(m0, b0, 1) STEP16(m1, b1, 5) STEP16(m2, b2, 9)  STEP16(m3, b3, 13)
    STEP16(m0, b0, 2) STEP16(m1, b1, 6) STEP16(m2, b2, 10) STEP16(m3, b3, 14)
    STEP16(m0, b0, 3) STEP16(m1, b1, 7) STEP16(m2, b2, 11) STEP16(m3, b3, 15)
    // combine sub-chains (left covers smaller i; strict > => first-occurrence)
    { bool g = m1 > m0; m0 = g ? m1 : m0; b0 = g ? b1 : b0; }
    { bool g = m3 > m2; m2 = g ? m3 : m2; b2 = g ? b3 : b2; }
    { bool g = m2 > m0; m0 = g ? m2 : m0; b0 = g ? b2 : b0; }

    const int par = t & 1;
    part_s[par][w][j] = make_float2(m0, __int_as_float(b0));

    // RAW barrier WITHOUT vmcnt drain: LDS writes ordered (lgkmcnt(0)),
    // global prefetch loads stay in flight across the barrier.
    asm volatile("s_waitcnt lgkmcnt(0)\n\ts_barrier" ::: "memory");

    // combine partials in ascending wave order (i ascending), strict >
    float2 p0 = part_s[par][0][j];
    float2 p1 = part_s[par][1][j];
    float2 p2 = part_s[par][2][j];
    float2 p3 = part_s[par][3][j];
    float bv = p0.x; int bidx = __float_as_int(p0.y);
    { bool g = p1.x > bv; bv = g ? p1.x : bv; bidx = g ? __float_as_int(p1.y) : bidx; }
    { bool g = p2.x > bv; bv = g ? p2.x : bv; bidx = g ? __float_as_int(p2.y) : bidx; }
    { bool g = p3.x > bv; bv = g ? p3.x : bv; bidx = g ? __float_as_int(p3.y) : bidx; }

    alpha = bv + xv;
    if (w == 0) bp_s[(t - 1) * NN + j] = (unsigned char)bidx;
  }

  // final argmax over states: in-wave butterfly with explicit index
  // tie-break (smaller index wins) -> exact jnp.argmax; all waves converge.
  float best = alpha;
  int last = j;
#pragma unroll
  for (int mask = 1; mask < 64; mask <<= 1) {
    float ov = __shfl_xor(best, mask, 64);
    int oi = __shfl_xor(last, mask, 64);
    bool take = (ov > best) || (ov == best && oi < last);
    best = take ? ov : best;
    last = take ? oi : last;
  }
  const float lastf = (float)last;

  // tags[t] = last for all t >= slen-1 (identity backpointers), coalesced
  for (int t = slen - 1 + tid; t < TT; t += 256) out[b * TT + t] = lastf;

  if (tid == 0) {
    // scores: exact fp32 value (d_out is float32)
    out[BB * TT + b] = best;

    // traceback: tags[t] = bp_{t+1}[tags[t+1]], bp_{t+1} stored at LDS row t.
    // tid0 is in wave 0 which wrote bp_s -> in-order DS pipe, no wait needed.
    int tag = last;
    for (int t = slen - 2; t >= 0; --t) {
      tag = bp_s[t * NN + tag];
      out[b * TT + t] = (float)tag;
    }
  }
}

extern "C" void kernel_launch(void* const* d_in, const int* in_sizes, int n_in,
                              void* d_out, int out_size, void* d_ws, size_t ws_size,
                              hipStream_t stream) {
  const float* x = (const float*)d_in[0];
  const int* seq_len = (const int*)d_in[1];
  const float* trans = (const float*)d_in[2];
  float* out = (float*)d_out;

  crf_viterbi_kernel<<<BB, 256, 0, stream>>>(x, seq_len, trans, out);
}

// Round 8
// 802.801 us; speedup vs baseline: 15.8030x; 1.1751x over previous
//
#include <hip/hip_runtime.h>

#define BB 256
#define TT 2048
#define NN 64

// DPP quad_perm cross-lane (pure VALU, no LDS): xor1 = [1,0,3,2] = 0xB1,
// xor2 = [2,3,0,1] = 0x4E
__device__ __forceinline__ int dpp_xor1_i(int v) {
  return __builtin_amdgcn_update_dpp(v, v, 0xB1, 0xF, 0xF, true);
}
__device__ __forceinline__ int dpp_xor2_i(int v) {
  return __builtin_amdgcn_update_dpp(v, v, 0x4E, 0xF, 0xF, true);
}
__device__ __forceinline__ float dpp_xor1_f(float v) {
  return __int_as_float(dpp_xor1_i(__float_as_int(v)));
}
__device__ __forceinline__ float dpp_xor2_f(float v) {
  return __int_as_float(dpp_xor2_i(__float_as_int(v)));
}

// one reduction link: strict > keeps lower index on ties (first-occurrence)
#define LINK(mq, bq, val, idx)        \
  {                                   \
    float c_ = (val);                 \
    bool g_ = c_ > (mq);              \
    (mq) = g_ ? c_ : (mq);            \
    (bq) = g_ ? (idx) : (bq);         \
  }

__global__ __launch_bounds__(256, 1)
void crf_viterbi_kernel(const float* __restrict__ x,
                        const int* __restrict__ seq_len,
                        const float* __restrict__ trans,
                        float* __restrict__ out) {
  const int b = blockIdx.x;
  const int tid = threadIdx.x;
  const int lane = tid & 63;
  const int w = tid >> 6;        // wave id 0..3
  const int c = lane >> 2;       // local column 0..15
  const int q = lane & 3;        // i-quarter 0..3
  const int jc = (w << 4) + c;   // global output column this lane serves
  const int iq = q << 4;         // this lane's i-range start

  // alpha ping-pong (tiny) + byte backpointers; sync payload is only the
  // 64 new alpha floats per step (vs 4x64 float2 partials in R7).
  __shared__ __align__(16) float alpha_s[2][NN];
  __shared__ unsigned char bp_s[(TT - 1) * NN];  // 131008 B

  const float* xb = x + (size_t)b * TT * NN;
  const int slen = seq_len[b];

  // this lane's trans slice: rows [iq, iq+16), column jc
  float tc[16];
#pragma unroll
  for (int k = 0; k < 16; ++k) tc[k] = trans[(iq + k) * NN + jc];

  // init alpha0 = x[:,0] (wave 0 writes; one full sync before the loop)
  if (w == 0) alpha_s[0][lane] = xb[lane];
  __syncthreads();

  // 2-deep x prefetch for column jc (4 lanes/quad load same addr, harmless);
  // raw barriers below never drain vmcnt -> these stay in flight.
  float xn1 = xb[NN + jc];
  float xn2 = xb[2 * NN + jc];

  for (int t = 1; t < slen; ++t) {
    float xv = xn1;
    xn1 = xn2;
    {
      int tn = (t + 2 < TT) ? (t + 2) : (TT - 1);  // clamped, stays in batch
      xn2 = xb[(size_t)tn * NN + jc];
    }
    const int pr = (t + 1) & 1;  // read parity (t=1 reads buf 0)
    const int pw = t & 1;        // write parity

    // 16 candidates for (i in [iq,iq+16)) -> 4 sub-chains of 4 (dep depth ~6)
    float4 a0 = *reinterpret_cast<const float4*>(&alpha_s[pr][iq + 0]);
    float4 a1 = *reinterpret_cast<const float4*>(&alpha_s[pr][iq + 4]);
    float4 a2 = *reinterpret_cast<const float4*>(&alpha_s[pr][iq + 8]);
    float4 a3 = *reinterpret_cast<const float4*>(&alpha_s[pr][iq + 12]);

    float m0 = a0.x + tc[0]; int b0 = iq + 0;
    float m1 = a1.x + tc[4]; int b1 = iq + 4;
    float m2 = a2.x + tc[8]; int b2 = iq + 8;
    float m3 = a3.x + tc[12]; int b3 = iq + 12;
    LINK(m0, b0, a0.y + tc[1], iq + 1)
    LINK(m1, b1, a1.y + tc[5], iq + 5)
    LINK(m2, b2, a2.y + tc[9], iq + 9)
    LINK(m3, b3, a3.y + tc[13], iq + 13)
    LINK(m0, b0, a0.z + tc[2], iq + 2)
    LINK(m1, b1, a1.z + tc[6], iq + 6)
    LINK(m2, b2, a2.z + tc[10], iq + 10)
    LINK(m3, b3, a3.z + tc[14], iq + 14)
    LINK(m0, b0, a0.w + tc[3], iq + 3)
    LINK(m1, b1, a1.w + tc[7], iq + 7)
    LINK(m2, b2, a2.w + tc[11], iq + 11)
    LINK(m3, b3, a3.w + tc[15], iq + 15)
    // combine sub-chains (left covers smaller i; strict > = first-occurrence)
    { bool g = m1 > m0; m0 = g ? m1 : m0; b0 = g ? b1 : b0; }
    { bool g = m3 > m2; m2 = g ? m3 : m2; b2 = g ? b3 : b2; }
    { bool g = m2 > m0; m0 = g ? m2 : m0; b0 = g ? b2 : b0; }

    // cross-quarter combine via DPP (pure VALU): explicit index tie-break
    // (smaller i wins) keeps exact first-occurrence semantics.
    {
      float pv = dpp_xor1_f(m0);
      int pi = dpp_xor1_i(b0);
      bool take = (pv > m0) || (pv == m0 && pi < b0);
      m0 = take ? pv : m0;
      b0 = take ? pi : b0;
    }
    {
      float pv = dpp_xor2_f(m0);
      int pi = dpp_xor2_i(b0);
      bool take = (pv > m0) || (pv == m0 && pi < b0);
      m0 = take ? pv : m0;
      b0 = take ? pi : b0;
    }

    // one lane per column publishes alpha & bp
    if (q == 0) {
      alpha_s[pw][jc] = m0 + xv;
      bp_s[(t - 1) * NN + jc] = (unsigned char)b0;
    }

    // raw barrier WITHOUT vmcnt drain: LDS writes ordered (lgkmcnt(0)),
    // x-prefetch loads stay in flight across the barrier.
    asm volatile("s_waitcnt lgkmcnt(0)\n\ts_barrier" ::: "memory");
  }

  // final argmax over states (all waves redundantly; exact jnp.argmax)
  const int pf = (slen - 1) & 1;
  float best = alpha_s[pf][lane];
  int last = lane;
#pragma unroll
  for (int mask = 1; mask < 64; mask <<= 1) {
    float ov = __shfl_xor(best, mask, 64);
    int oi = __shfl_xor(last, mask, 64);
    bool take = (ov > best) || (ov == best && oi < last);
    best = take ? ov : best;
    last = take ? oi : last;
  }
  const float lastf = (float)last;

  // tags[t] = last for all t >= slen-1 (identity backpointers), coalesced
  for (int t = slen - 1 + tid; t < TT; t += 256) out[b * TT + t] = lastf;

  if (tid == 0) {
    // scores: exact fp32 value (d_out is float32)
    out[BB * TT + b] = best;

    // traceback: tags[t] = bp_{t+1}[tags[t+1]], bp_{t+1} at LDS row t
    // (all bp writes are before the loop's final barrier -> visible)
    int tag = last;
    for (int t = slen - 2; t >= 0; --t) {
      tag = bp_s[t * NN + tag];
      out[b * TT + t] = (float)tag;
    }
  }
}

extern "C" void kernel_launch(void* const* d_in, const int* in_sizes, int n_in,
                              void* d_out, int out_size, void* d_ws, size_t ws_size,
                              hipStream_t stream) {
  const float* x = (const float*)d_in[0];
  const int* seq_len = (const int*)d_in[1];
  const float* trans = (const float*)d_in[2];
  float* out = (float*)d_out;

  crf_viterbi_kernel<<<BB, 256, 0, stream>>>(x, seq_len, trans, out);
}

// Round 9
// 792.867 us; speedup vs baseline: 16.0010x; 1.0125x over previous
//
#include <hip/hip_runtime.h>

#define BB 256
#define TT 2048
#define NN 64
#define CHK 512

// DPP row-rotate (within each 16-lane row). K must be compile-time.
template <int K>
__device__ __forceinline__ int dpp_ror_i(int v) {
  return __builtin_amdgcn_update_dpp(0, v, 0x120 | K, 0xF, 0xF, true);
}
template <int K>
__device__ __forceinline__ float dpp_ror_f(float v) {
  return __int_as_float(dpp_ror_i<K>(__float_as_int(v)));
}

__global__ __launch_bounds__(256, 1)
void crf_viterbi_kernel(const float* __restrict__ x,
                        const int* __restrict__ seq_len,
                        const float* __restrict__ trans,
                        float* __restrict__ out) {
  const int b = blockIdx.x;
  const int tid = threadIdx.x;
  const int lane = tid & 63;
  const int w = tid >> 6;       // wave id 0..3
  const int c = lane & 15;      // column within wave's 16
  const int jc = (w << 4) + c;  // global output column this lane serves
                                // row q = lane>>4 = i-quarter (implicit)

  __shared__ __align__(16) float alpha_s[2][NN];
  __shared__ unsigned char bp_s[(TT - 1) * NN];  // 131008 B backpointers
  __shared__ int map_s[4][NN];                   // chunk traceback maps

  const float* xb = x + (size_t)b * TT * NN;
  const int slen = seq_len[b];

  // Rotation source indices, derived with the SAME DPP used on alpha
  // (direction-proof): idxv[k][lane] = source lane of rotation k = the i
  // whose alpha arrives at this lane. Covers this lane's 16-row bijectively.
  int idxv[16];
  idxv[0] = lane;
  idxv[1] = dpp_ror_i<1>(lane);   idxv[2] = dpp_ror_i<2>(lane);
  idxv[3] = dpp_ror_i<3>(lane);   idxv[4] = dpp_ror_i<4>(lane);
  idxv[5] = dpp_ror_i<5>(lane);   idxv[6] = dpp_ror_i<6>(lane);
  idxv[7] = dpp_ror_i<7>(lane);   idxv[8] = dpp_ror_i<8>(lane);
  idxv[9] = dpp_ror_i<9>(lane);   idxv[10] = dpp_ror_i<10>(lane);
  idxv[11] = dpp_ror_i<11>(lane); idxv[12] = dpp_ror_i<12>(lane);
  idxv[13] = dpp_ror_i<13>(lane); idxv[14] = dpp_ror_i<14>(lane);
  idxv[15] = dpp_ror_i<15>(lane);

  float tcv[16];
#pragma unroll
  for (int k = 0; k < 16; ++k) tcv[k] = trans[idxv[k] * NN + jc];

  // init alpha0 = x[:,0]
  if (w == 0) alpha_s[0][lane] = xb[lane];
  __syncthreads();

  // 2-deep x prefetch for column jc; raw barriers never drain vmcnt.
  float xn1 = xb[NN + jc];
  float xn2 = xb[2 * NN + jc];

  for (int t = 1; t < slen; ++t) {
    float xv = xn1;
    xn1 = xn2;
    {
      int tn = (t + 2 < TT) ? (t + 2) : (TT - 1);
      xn2 = xb[(size_t)tn * NN + jc];
    }
    const int pr = (t + 1) & 1;  // read parity (t=1 reads buf 0)
    const int pw = t & 1;        // write parity

    // one b32 per lane: av[lane] = alpha[lane]
    float av = alpha_s[pr][lane];

    // 16 candidates via DPP row-rotations; 4 sub-chains of 4 (dep ~6 links).
#define CAND(K) (dpp_ror_f<K>(av) + tcv[K])
#define LNK(K, mq, bq)                                       \
    {                                                        \
      float c_ = CAND(K);                                    \
      bool g_ = c_ > (mq);                                   \
      (mq) = g_ ? c_ : (mq);                                 \
      (bq) = g_ ? idxv[K] : (bq);                            \
    }
    float m0 = av + tcv[0]; int b0 = idxv[0];
    float m1 = CAND(4);     int b1 = idxv[4];
    float m2 = CAND(8);     int b2 = idxv[8];
    float m3 = CAND(12);    int b3 = idxv[12];
    LNK(1, m0, b0) LNK(5, m1, b1) LNK(9,  m2, b2) LNK(13, m3, b3)
    LNK(2, m0, b0) LNK(6, m1, b1) LNK(10, m2, b2) LNK(14, m3, b3)
    LNK(3, m0, b0) LNK(7, m1, b1) LNK(11, m2, b2) LNK(15, m3, b3)
    { bool g = m1 > m0; m0 = g ? m1 : m0; b0 = g ? b1 : b0; }
    { bool g = m3 > m2; m2 = g ? m3 : m2; b2 = g ? b3 : b2; }
    { bool g = m2 > m0; m0 = g ? m2 : m0; b0 = g ? b2 : b0; }
#undef LNK
#undef CAND

    // cross-quarter combine (rows q: lanes +-16, +-32)
    {
      float pm = __shfl_xor(m0, 16, 64);
      int pb = __shfl_xor(b0, 16, 64);
      bool g = pm > m0; m0 = g ? pm : m0; b0 = g ? pb : b0;
    }
    {
      float pm = __shfl_xor(m0, 32, 64);
      int pb = __shfl_xor(b0, 32, 64);
      bool g = pm > m0; m0 = g ? pm : m0; b0 = g ? pb : b0;
    }

    // row-0 lanes publish alpha & bp for this wave's 16 columns
    if (lane < 16) {
      alpha_s[pw][jc] = m0 + xv;
      bp_s[(t - 1) * NN + jc] = (unsigned char)b0;
    }
    // raw barrier WITHOUT vmcnt drain: LDS ordered, prefetch stays in flight
    asm volatile("s_waitcnt lgkmcnt(0)\n\ts_barrier" ::: "memory");
  }

  // final argmax over states (exact; smaller index wins ties)
  const int pf = (slen - 1) & 1;
  float best = alpha_s[pf][lane];
  int last = lane;
#pragma unroll
  for (int mask = 1; mask < 64; mask <<= 1) {
    float ov = __shfl_xor(best, mask, 64);
    int oi = __shfl_xor(last, mask, 64);
    bool take = (ov > best) || (ov == best && oi < last);
    best = take ? ov : best;
    last = take ? oi : last;
  }
  const float lastf = (float)last;
  const int bTT = b * TT;

  // tags[t] = last for all t >= slen-1 (identity region), coalesced
  for (int t = slen - 1 + tid; t < TT; t += 256) out[bTT + t] = lastf;
  if (tid == 0) out[BB * TT + b] = best;  // scores: exact fp32

  // ---- parallel traceback ----
  // Phase A: lane e of wave w composes chunk w's bp map from every state.
  // Valid bp rows are 0..slen-2 (row r maps tag_{r+1} -> tag_r).
  const int lo = CHK * w;
  const int hi = ((CHK * (w + 1) - 1) < (slen - 2)) ? (CHK * (w + 1) - 1)
                                                    : (slen - 2);
  {
    int s = lane;
    for (int r = hi; r >= lo; --r) s = bp_s[r * NN + s];
    map_s[w][lane] = s;
  }
  __syncthreads();

  // Fold maps (redundant in every thread): entry state per chunk.
  // e3 = tag at top of chunk 3 feed-in (= last; identity region covers gaps)
  const int e3 = last;
  const int e2 = map_s[3][e3];
  const int e1 = map_s[2][e2];
  const int e0 = map_s[1][e1];
  const int entry = (w == 3) ? e3 : (w == 2) ? e2 : (w == 1) ? e1 : e0;

  // Phase B: one lane per wave re-traces its chunk writing tags.
  if (lane == 0) {
    int s = entry;
    for (int r = hi; r >= lo; --r) {
      s = bp_s[r * NN + s];
      out[bTT + r] = (float)s;
    }
  }
}

extern "C" void kernel_launch(void* const* d_in, const int* in_sizes, int n_in,
                              void* d_out, int out_size, void* d_ws, size_t ws_size,
                              hipStream_t stream) {
  const float* x = (const float*)d_in[0];
  const int* seq_len = (const int*)d_in[1];
  const float* trans = (const float*)d_in[2];
  float* out = (float*)d_out;

  crf_viterbi_kernel<<<BB, 256, 0, stream>>>(x, seq_len, trans, out);
}